// Round 15
// baseline (134.147 us; speedup 1.0000x reference)
//
#include <hip/hip_runtime.h>
#include <math.h>

// Problem constants
#define E_     64     // embedding dim == wavefront size
#define ND_    40     // diseases per visit
#define NM_    30     // medications per visit
#define NSTEP_ 31     // NM+1 decode steps
#define VO_    133    // VM+2 output vocab
#define J3_    192    // 3*E (GRU gates)
#define NROW_  8192   // B*S
#define RPB_   16     // rows per block (= M-tile, all real)
#define SOS_   131    // VM
#define NCP_   196    // prologue sC stride (f32)

typedef __attribute__((ext_vector_type(8))) short short8;
typedef __attribute__((ext_vector_type(4))) float f32x4;

__device__ __forceinline__ float sigmoidf_(float x){ return 1.f/(1.f+__expf(-x)); }
__device__ __forceinline__ float tanhf_(float x){
  float ax = fabsf(x);
  float t = 1.f - 2.f/(__expf(2.f*ax)+1.f);   // stable, saturates to 1
  return copysignf(t, x);
}
__device__ __forceinline__ unsigned short f2bf(float f){
  union { float f; unsigned u; } x; x.f = f;
  unsigned r = (x.u + 0x7fffu + ((x.u >> 16) & 1u)) >> 16;  // RNE
  return (unsigned short)r;
}
__device__ __forceinline__ short8 pack8_(const float* __restrict__ s){
  short8 f;
  #pragma unroll
  for (int j=0;j<8;++j) f[j] = (short)f2bf(s[j]);
  return f;
}

// lgkm-only barrier: no vmcnt drain — in-flight output stores never waited on.
__device__ __forceinline__ void bar_lds(){
  asm volatile("s_waitcnt lgkmcnt(0)" ::: "memory");
  __builtin_amdgcn_s_barrier();
  asm volatile("" ::: "memory");
}

// ---------------------------------------------------------------------------
// Kernel A: P_med[v][j] = sum_e med_table[v][e] * W_ih[j][64+e]   (134x192)
// ---------------------------------------------------------------------------
__global__ __launch_bounds__(256) void k_pmed(const float* __restrict__ mt,
    const float* __restrict__ wih, float* __restrict__ pmed){
  int o = blockIdx.x*256 + threadIdx.x;
  if (o >= 134*J3_) return;
  int v = o / J3_, j = o - v*J3_;
  const float* mr = mt + v*E_;
  const float* wr = wih + j*128 + E_;
  float a = 0.f;
  #pragma unroll
  for (int k=0;k<E_;k++) a = fmaf(mr[k], wr[k], a);
  pmed[o] = a;
}

// ---------------------------------------------------------------------------
// Wave-specialized fused decoder, ONE barrier per step (round-14 structure,
// register-honest build):
//  - __launch_bounds__(512) with NO min-waves: r14's (512,4) made the
//    compiler chase the 64-VGPR tier and spill ~10 regs per iteration
//    (FETCH +9MB, WRITE +32MB). Natural alloc (~100) still gives 2 blocks/CU.
//  - s_setprio(1) around GRU waves' MFMA+pointwise (T5: role-split exists;
//    the GRU chain gates the next barrier, softmax waves are tolerant).
//  - zero-B third MFMA pair only on wave 4 (waves 5-7 skip it).
//  - Waves 0-3: own W_hh n-tiles {w, w+4, w+8}; 3 MFMA accumulators ARE
//    gh_r/gh_z/gh_n for (rows l4*4+i, col w*16+l15) — GRU in-register,
//    h_{t+1} -> double-buffered hA. No sC round-trip.
//  - Waves 4-7: logits in-register, exp + 16-lane butterfly -> sPart;
//    log/store finish delayed 1 iter. Output step t-2 at iter t.
// ---------------------------------------------------------------------------
__global__ __launch_bounds__(512) void k_main(
    const int* __restrict__ dis, const float* __restrict__ dmask,
    const float* __restrict__ dt, const float* __restrict__ aw,
    const int* __restrict__ meds,
    const float* __restrict__ whh, const float* __restrict__ bhh,
    const float* __restrict__ wih, const float* __restrict__ bih,
    const float* __restrict__ wo, const float* __restrict__ wob,
    const float* __restrict__ mt, const float* __restrict__ pmed,
    float* __restrict__ out)
{
  __shared__ __align__(16) unsigned short hA[2][RPB_*E_]; // 4KB dbuf bf16 h
  __shared__ __align__(16) float sCp[RPB_*NCP_];          // 12.5KB prologue gi
  __shared__ __align__(16) float sPart[2][RPB_][4];       // 512B exp partials
  __shared__ int sLM[RPB_*32];                            // 2KB last-med idx

  const int tid = threadIdx.x;
  const int w = tid >> 6, l = tid & 63;
  const int l15 = l & 15, l4 = l >> 4;
  const int rowbase = blockIdx.x * RPB_;
  const bool isg = (w < 4);                 // GRU wave?
  const int w4 = w - 4;                     // softmax wave index
  const int dcol = (w & 3)*16 + l15;        // GRU wave's gate column

  // ---- last-med indices ----
  {
    int rr = tid >> 5, tt = tid & 31;
    if (tt < NSTEP_)
      sLM[rr*32 + tt] = (tt==0) ? SOS_ : meds[(size_t)(rowbase+rr)*NM_ + (tt-1)];
  }

  // ======== prologue: attention ctx for rows 2w, 2w+1 (h-independent) ====
  float wd = aw[E_ + l];
  #pragma unroll 1
  for (int r2 = 0; r2 < 2; ++r2){
    int rr = 2*w + r2;
    const int*   drow = dis   + (size_t)(rowbase+rr)*ND_;
    const float* mrow = dmask + (size_t)(rowbase+rr)*ND_;
    float dreg[ND_], sc[ND_];
    float mx = -INFINITY;
    #pragma unroll
    for (int n = 0; n < ND_; ++n){
      float d = dt[(size_t)drow[n]*E_ + l];
      dreg[n] = d;
      float p = d * wd;
      #pragma unroll
      for (int m=1;m<64;m<<=1) p += __shfl_xor(p, m);
      sc[n] = p + mrow[n];
      mx = fmaxf(mx, sc[n]);
    }
    float ss = 0.f, ctx = 0.f;
    #pragma unroll
    for (int n = 0; n < ND_; ++n){
      float e = __expf(sc[n]-mx);
      ss += e;
      ctx = fmaf(e, dreg[n], ctx);
    }
    ctx /= ss;
    hA[0][rr*E_ + (l ^ ((rr&7)<<3))] = f2bf(ctx);  // swizzled A-tile row
  }
  __syncthreads();

  // ======== prologue: gi = ctx @ W_ih_left^T (all 8 waves, MFMA) ========
  {
    short8 A00 = *(const short8*)&hA[0][l15*E_ + (((l4  ) ^ (l15&7))<<3)];
    short8 A01 = *(const short8*)&hA[0][l15*E_ + (((l4+4) ^ (l15&7))<<3)];
    #pragma unroll
    for (int jj = 0; jj < 2; ++jj){
      int n = w + 8*jj;
      if (n < 12){                          // 12 tiles cover 192 cols
        int c = n*16 + l15;
        short8 Bp0 = pack8_(wih + (size_t)c*128 + l4*8);
        short8 Bp1 = pack8_(wih + (size_t)c*128 + 32 + l4*8);
        f32x4 cc = {0.f,0.f,0.f,0.f};
        cc = __builtin_amdgcn_mfma_f32_16x16x32_bf16(A00, Bp0, cc, 0,0,0);
        cc = __builtin_amdgcn_mfma_f32_16x16x32_bf16(A01, Bp1, cc, 0,0,0);
        #pragma unroll
        for (int i=0;i<4;i++) sCp[(l4*4+i)*NCP_ + c] = cc[i];
      }
    }
  }
  __syncthreads();

  // ======== per-lane loop-invariant state ========
  short8 B0a, B1a, B0b, B1b, B0c, B1c;      // 3 B-frag pairs (both roles)
  float gia[4], giz[4], gin[4], hrv[4];
  float pmr[4], pmz[4], pmn[4];
  float bhn = 0.f;
  float wbv0 = 0.f, wbv1 = 0.f, wbv2 = -1e30f;
  float *pR0=0, *pR1=0, *pR2=0, *pR3=0;
  const bool act2 = (w == 4);               // softmax wave with tile 8
  const bool v2l  = (w == 4) && (l15 < 5);  // tile-8 col valid

  if (isg){
    float bi0 = bih[dcol] + bhh[dcol];
    float bi1 = bih[dcol+64] + bhh[dcol+64];
    float bi2 = bih[dcol+128];
    bhn = bhh[dcol+128];
    float h0 = mt[SOS_*E_ + dcol];
    #pragma unroll
    for (int i=0;i<4;++i){
      int r = l4*4 + i;
      gia[i] = sCp[r*NCP_ + dcol]       + bi0;
      giz[i] = sCp[r*NCP_ + dcol + 64]  + bi1;
      gin[i] = sCp[r*NCP_ + dcol + 128] + bi2;
      hrv[i] = h0;
      int lm = sLM[r*32];
      const float* pp = pmed + (size_t)lm*J3_ + dcol;
      pmr[i] = pp[0]; pmz[i] = pp[64]; pmn[i] = pp[128];
      hA[0][r*E_ + ((((dcol>>3) ^ (r&7))<<3) + (dcol&7))] = f2bf(h0);
    }
    { int c = (w)*16 + l15;       B0a = pack8_(whh + (size_t)c*E_ + l4*8);
                                  B1a = pack8_(whh + (size_t)c*E_ + 32 + l4*8); }
    { int c = (w+4)*16 + l15;     B0b = pack8_(whh + (size_t)c*E_ + l4*8);
                                  B1b = pack8_(whh + (size_t)c*E_ + 32 + l4*8); }
    { int c = (w+8)*16 + l15;     B0c = pack8_(whh + (size_t)c*E_ + l4*8);
                                  B1c = pack8_(whh + (size_t)c*E_ + 32 + l4*8); }
  } else {
    int c0 = w4*16 + l15;                   // < 64, always valid
    int c1 = (w4+4)*16 + l15;               // < 128, always valid
    wbv0 = wob[c0];
    wbv1 = wob[c1];
    B0a = pack8_(wo + (size_t)c0*E_ + l4*8);
    B1a = pack8_(wo + (size_t)c0*E_ + 32 + l4*8);
    B0b = pack8_(wo + (size_t)c1*E_ + l4*8);
    B1b = pack8_(wo + (size_t)c1*E_ + 32 + l4*8);
    short8 z = {0,0,0,0,0,0,0,0};
    B0c = z; B1c = z;
    if (act2){
      int c2 = 128 + l15;
      if (c2 < VO_){
        wbv2 = wob[c2];
        B0c = pack8_(wo + (size_t)c2*E_ + l4*8);
        B1c = pack8_(wo + (size_t)c2*E_ + 32 + l4*8);
      }
    }
    pR0 = out + (size_t)(rowbase + l4*4 + 0)*NSTEP_*VO_;
    pR1 = out + (size_t)(rowbase + l4*4 + 1)*NSTEP_*VO_;
    pR2 = out + (size_t)(rowbase + l4*4 + 2)*NSTEP_*VO_;
    pR3 = out + (size_t)(rowbase + l4*4 + 3)*NSTEP_*VO_;
  }
  f32x4 LP0 = {0.f,0.f,0.f,0.f}, LP1 = LP0, LP2 = LP0;
  __syncthreads();

  // ======== main loop: NSTEP_+2 iterations, ONE barrier each ========
  for (int t = 0; t <= NSTEP_+1; ++t){
    const unsigned short* hc = hA[t&1];
    if (isg){
      if (t < NSTEP_){
        __builtin_amdgcn_s_setprio(1);      // GRU chain gates next barrier
        short8 A00 = *(const short8*)&hc[l15*E_ + (((l4  ) ^ (l15&7))<<3)];
        short8 A01 = *(const short8*)&hc[l15*E_ + (((l4+4) ^ (l15&7))<<3)];
        f32x4 c0 = {0.f,0.f,0.f,0.f}, c1 = c0, c2 = c0;
        c0 = __builtin_amdgcn_mfma_f32_16x16x32_bf16(A00, B0a, c0, 0,0,0);
        c0 = __builtin_amdgcn_mfma_f32_16x16x32_bf16(A01, B1a, c0, 0,0,0);
        c1 = __builtin_amdgcn_mfma_f32_16x16x32_bf16(A00, B0b, c1, 0,0,0);
        c1 = __builtin_amdgcn_mfma_f32_16x16x32_bf16(A01, B1b, c1, 0,0,0);
        c2 = __builtin_amdgcn_mfma_f32_16x16x32_bf16(A00, B0c, c2, 0,0,0);
        c2 = __builtin_amdgcn_mfma_f32_16x16x32_bf16(A01, B1c, c2, 0,0,0);
        unsigned short* hnw = hA[(t+1)&1];
        #pragma unroll
        for (int i=0;i<4;++i){
          float ir = gia[i] + pmr[i] + c0[i];
          float iz = giz[i] + pmz[i] + c1[i];
          float nn = gin[i] + pmn[i];
          float hn = c2[i] + bhn;
          float rg = sigmoidf_(ir), zg = sigmoidf_(iz);
          float ng = tanhf_(nn + rg*hn);
          float h  = (1.f - zg)*ng + zg*hrv[i];
          hrv[i] = h;
          int r = l4*4 + i;
          hnw[r*E_ + ((((dcol>>3) ^ (r&7))<<3) + (dcol&7))] = f2bf(h);
        }
        __builtin_amdgcn_s_setprio(0);
        if (t+1 < NSTEP_){
          #pragma unroll
          for (int i=0;i<4;++i){
            int r = l4*4 + i;
            int lm = sLM[r*32 + t + 1];
            const float* pp = pmed + (size_t)lm*J3_ + dcol;
            pmr[i] = pp[0]; pmz[i] = pp[64]; pmn[i] = pp[128];
          }
        }
      }
    } else {
      f32x4 LC0 = {0.f,0.f,0.f,0.f}, LC1 = LC0, LC2 = LC0;
      if (t >= 1 && t <= NSTEP_){
        short8 A00 = *(const short8*)&hc[l15*E_ + (((l4  ) ^ (l15&7))<<3)];
        short8 A01 = *(const short8*)&hc[l15*E_ + (((l4+4) ^ (l15&7))<<3)];
        LC0 = __builtin_amdgcn_mfma_f32_16x16x32_bf16(A00, B0a, LC0, 0,0,0);
        LC0 = __builtin_amdgcn_mfma_f32_16x16x32_bf16(A01, B1a, LC0, 0,0,0);
        LC1 = __builtin_amdgcn_mfma_f32_16x16x32_bf16(A00, B0b, LC1, 0,0,0);
        LC1 = __builtin_amdgcn_mfma_f32_16x16x32_bf16(A01, B1b, LC1, 0,0,0);
        if (act2){                           // only wave 4 has a real tile 8
          LC2 = __builtin_amdgcn_mfma_f32_16x16x32_bf16(A00, B0c, LC2, 0,0,0);
          LC2 = __builtin_amdgcn_mfma_f32_16x16x32_bf16(A01, B1c, LC2, 0,0,0);
        }
        #pragma unroll
        for (int i=0;i<4;++i){
          LC0[i] += wbv0; LC1[i] += wbv1; LC2[i] += wbv2;
        }
        float e0 = __expf(LC0[0]) + __expf(LC1[0]) + (act2 ? __expf(LC2[0]) : 0.f);
        float e1 = __expf(LC0[1]) + __expf(LC1[1]) + (act2 ? __expf(LC2[1]) : 0.f);
        float e2 = __expf(LC0[2]) + __expf(LC1[2]) + (act2 ? __expf(LC2[2]) : 0.f);
        float e3 = __expf(LC0[3]) + __expf(LC1[3]) + (act2 ? __expf(LC2[3]) : 0.f);
        #pragma unroll
        for (int mm=1; mm<16; mm<<=1){      // butterfly within l15 group
          e0 += __shfl_xor(e0, mm); e1 += __shfl_xor(e1, mm);
          e2 += __shfl_xor(e2, mm); e3 += __shfl_xor(e3, mm);
        }
        if (l15 == 0){
          int cb = t & 1;
          sPart[cb][l4*4+0][w4] = e0;
          sPart[cb][l4*4+1][w4] = e1;
          sPart[cb][l4*4+2][w4] = e2;
          sPart[cb][l4*4+3][w4] = e3;
        }
      }
      if (t >= 2){
        int pb = (t & 1) ^ 1;
        f32x4 q0 = *(const f32x4*)&sPart[pb][l4*4+0][0];
        f32x4 q1 = *(const f32x4*)&sPart[pb][l4*4+1][0];
        f32x4 q2 = *(const f32x4*)&sPart[pb][l4*4+2][0];
        f32x4 q3 = *(const f32x4*)&sPart[pb][l4*4+3][0];
        float lg0 = __logf(q0[0]+q0[1]+q0[2]+q0[3]);
        float lg1 = __logf(q1[0]+q1[1]+q1[2]+q1[3]);
        float lg2 = __logf(q2[0]+q2[1]+q2[2]+q2[3]);
        float lg3 = __logf(q3[0]+q3[1]+q3[2]+q3[3]);
        int c0 = w4*16 + l15, c1 = (w4+4)*16 + l15;
        pR0[c0] = LP0[0] - lg0;  pR0[c1] = LP1[0] - lg0;
        pR1[c0] = LP0[1] - lg1;  pR1[c1] = LP1[1] - lg1;
        pR2[c0] = LP0[2] - lg2;  pR2[c1] = LP1[2] - lg2;
        pR3[c0] = LP0[3] - lg3;  pR3[c1] = LP1[3] - lg3;
        if (v2l){
          int c2 = 128 + l15;
          pR0[c2] = LP2[0] - lg0;
          pR1[c2] = LP2[1] - lg1;
          pR2[c2] = LP2[2] - lg2;
          pR3[c2] = LP2[3] - lg3;
        }
        pR0 += VO_; pR1 += VO_; pR2 += VO_; pR3 += VO_;
      }
      if (t >= 1 && t <= NSTEP_){ LP0 = LC0; LP1 = LC1; LP2 = LC2; }
    }
    bar_lds();
  }
}

extern "C" void kernel_launch(void* const* d_in, const int* in_sizes, int n_in,
                              void* d_out, int out_size, void* d_ws, size_t ws_size,
                              hipStream_t stream){
  const int*   dis  = (const int*)  d_in[0];
  const int*   meds = (const int*)  d_in[2];
  const float* dmask= (const float*)d_in[3];
  const float* dt   = (const float*)d_in[6];
  const float* mt   = (const float*)d_in[7];
  const float* aw   = (const float*)d_in[8];
  const float* wih  = (const float*)d_in[10];
  const float* whh  = (const float*)d_in[11];
  const float* bih  = (const float*)d_in[12];
  const float* bhh  = (const float*)d_in[13];
  const float* wo   = (const float*)d_in[14];
  const float* wob  = (const float*)d_in[15];
  float* outp = (float*)d_out;
  float* pmed = (float*)d_ws;                     // 134*192 f32

  k_pmed<<<(134*J3_+255)/256, 256, 0, stream>>>(mt, wih, pmed);
  k_main<<<NROW_/RPB_, 512, 0, stream>>>(dis, dmask, dt, aw, meds,
                                         whh, bhh, wih, bih, wo, wob,
                                         mt, pmed, outp);
}

// Round 16
// 98.330 us; speedup vs baseline: 1.3643x; 1.3643x over previous
//
#include <hip/hip_runtime.h>
#include <math.h>

// Problem constants
#define E_     64     // embedding dim == wavefront size
#define ND_    40     // diseases per visit
#define NM_    30     // medications per visit
#define NSTEP_ 31     // NM+1 decode steps
#define VO_    133    // VM+2 output vocab
#define J3_    192    // 3*E (GRU gates)
#define NROW_  8192   // B*S
#define RPB_   16     // rows per block (= M-tile, all real)
#define SOS_   131    // VM
#define NC_    344    // sC stride (f32): 336 used cols + pad

typedef __attribute__((ext_vector_type(8))) short short8;
typedef __attribute__((ext_vector_type(4))) float f32x4;

__device__ __forceinline__ float sigmoidf_(float x){ return 1.f/(1.f+__expf(-x)); }
__device__ __forceinline__ float tanhf_(float x){
  float ax = fabsf(x);
  float t = 1.f - 2.f/(__expf(2.f*ax)+1.f);   // stable, saturates to 1
  return copysignf(t, x);
}
__device__ __forceinline__ unsigned short f2bf(float f){
  union { float f; unsigned u; } x; x.f = f;
  unsigned r = (x.u + 0x7fffu + ((x.u >> 16) & 1u)) >> 16;  // RNE
  return (unsigned short)r;
}
__device__ __forceinline__ short8 pack8_(const float* __restrict__ s){
  short8 f;
  #pragma unroll
  for (int j=0;j<8;++j) f[j] = (short)f2bf(s[j]);
  return f;
}

// lgkm-only barrier: does NOT drain vmcnt, so in-flight global stores
// (output stream) are never waited on at step boundaries.
__device__ __forceinline__ void bar_lds(){
  asm volatile("s_waitcnt lgkmcnt(0)" ::: "memory");
  __builtin_amdgcn_s_barrier();
  asm volatile("" ::: "memory");
}

// ---------------------------------------------------------------------------
// Kernel A: P_med[v][j] = sum_e med_table[v][e] * W_ih[j][64+e]   (134x192)
// ---------------------------------------------------------------------------
__global__ __launch_bounds__(256) void k_pmed(const float* __restrict__ mt,
    const float* __restrict__ wih, float* __restrict__ pmed){
  int o = blockIdx.x*256 + threadIdx.x;
  if (o >= 134*J3_) return;
  int v = o / J3_, j = o - v*J3_;
  const float* mr = mt + v*E_;
  const float* wr = wih + j*128 + E_;
  float a = 0.f;
  #pragma unroll
  for (int k=0;k<E_;k++) a = fmaf(mr[k], wr[k], a);
  pmed[o] = a;
}

// ---------------------------------------------------------------------------
// Fused cooperative decoder (round-10 configuration — session best, 97.9us).
// 512 blocks x 512 threads (8 waves), 16 rows/block = full M-tile,
// 2 blocks/CU resident (16 waves/CU, whole grid co-resident), VGPR=60.
// Per step: combined GEMM h_t(16x64) x [W_hh^T|wo^T](64x336) — 21 n-tiles
// split {w, w+8, w+16(w<5)} across 8 waves, B as register fragments;
// pointwise GRU 2 dims/thread; logits(t-1) softmax 32-wide (max-free:
// logits provably bounded, exp cannot overflow fp32).
// lgkm-only barriers; pmed loads for t+1 issued BEFORE step-t out stores.
// Measured equilibrium: ~3.1us/step, VALUBusy~50%, no saturated pipe; all
// structural variants tested (rounds 2-15) land at or above this time.
// ---------------------------------------------------------------------------
__global__ __launch_bounds__(512,4) void k_main(
    const int* __restrict__ dis, const float* __restrict__ dmask,
    const float* __restrict__ dt, const float* __restrict__ aw,
    const int* __restrict__ meds,
    const float* __restrict__ whh, const float* __restrict__ bhh,
    const float* __restrict__ wih, const float* __restrict__ bih,
    const float* __restrict__ wo, const float* __restrict__ wob,
    const float* __restrict__ mt, const float* __restrict__ pmed,
    float* __restrict__ out)
{
  __shared__ __align__(16) unsigned short hA[RPB_*E_];  // 2KB swizzled bf16 h
  __shared__ __align__(16) float sC[RPB_*NC_];          // 22KB GEMM out
  __shared__ int sLM[RPB_*32];                          // 2KB last-med idx

  const int tid = threadIdx.x;
  const int w = tid >> 6, l = tid & 63;
  const int l15 = l & 15, l4 = l >> 4;
  const int row = tid >> 5;                 // pointwise row (0..15)
  const int d0  = (tid & 31) * 2;           // pointwise dim pair
  const int rowbase = blockIdx.x * RPB_;
  const int grow = rowbase + row;

  // ---- last-med indices ----
  {
    int rr = tid >> 5, t = tid & 31;
    if (t < NSTEP_)
      sLM[rr*32 + t] = (t==0) ? SOS_ : meds[(size_t)(rowbase+rr)*NM_ + (t-1)];
  }

  // ======== prologue: attention ctx for rows 2w, 2w+1 (h-independent) ====
  float wd = aw[E_ + l];
  #pragma unroll 1
  for (int r2 = 0; r2 < 2; ++r2){
    int rr = 2*w + r2;
    const int*   drow = dis   + (size_t)(rowbase+rr)*ND_;
    const float* mrow = dmask + (size_t)(rowbase+rr)*ND_;
    float dreg[ND_], sc[ND_];
    float mx = -INFINITY;
    #pragma unroll
    for (int n = 0; n < ND_; ++n){
      float d = dt[(size_t)drow[n]*E_ + l];
      dreg[n] = d;
      float p = d * wd;
      #pragma unroll
      for (int m=1;m<64;m<<=1) p += __shfl_xor(p, m);
      sc[n] = p + mrow[n];
      mx = fmaxf(mx, sc[n]);
    }
    float ss = 0.f, ctx = 0.f;
    #pragma unroll
    for (int n = 0; n < ND_; ++n){
      float e = __expf(sc[n]-mx);
      ss += e;
      ctx = fmaf(e, dreg[n], ctx);
    }
    ctx /= ss;
    hA[rr*E_ + (l ^ ((rr&7)<<3))] = f2bf(ctx);   // swizzled A-tile row
  }
  __syncthreads();

  // ======== prologue: gi = ctx @ W_ih_left^T (cooperative MFMA) ========
  {
    short8 A00 = *(const short8*)&hA[l15*E_ + ((l4*8     ) ^ ((l15&7)<<3))];
    short8 A01 = *(const short8*)&hA[l15*E_ + ((32 + l4*8) ^ ((l15&7)<<3))];
    #pragma unroll
    for (int jj = 0; jj < 2; ++jj){
      int n = w + 8*jj;
      if (n < 12){                              // 12 tiles cover 192 cols
        int c = n*16 + l15;
        short8 B0 = pack8_(wih + (size_t)c*128 + l4*8);
        short8 B1 = pack8_(wih + (size_t)c*128 + 32 + l4*8);
        f32x4 cc = {0.f,0.f,0.f,0.f};
        cc = __builtin_amdgcn_mfma_f32_16x16x32_bf16(A00, B0, cc, 0,0,0);
        cc = __builtin_amdgcn_mfma_f32_16x16x32_bf16(A01, B1, cc, 0,0,0);
        #pragma unroll
        for (int i=0;i<4;i++) sC[(l4*4+i)*NC_ + c] = cc[i];
      }
    }
  }
  __syncthreads();
  // per-thread gi (row, dims d0..d0+1), fold biases
  float2 gir = *(const float2*)&sC[row*NC_ + d0];
  float2 giz = *(const float2*)&sC[row*NC_ + d0 + 64];
  float2 gin = *(const float2*)&sC[row*NC_ + d0 + 128];
  {
    float2 a = *(const float2*)&bih[d0],      b = *(const float2*)&bhh[d0];
    float2 c = *(const float2*)&bih[d0+64],   d = *(const float2*)&bhh[d0+64];
    float2 e = *(const float2*)&bih[d0+128];
    gir.x += a.x + b.x; gir.y += a.y + b.y;
    giz.x += c.x + d.x; giz.y += c.y + d.y;
    gin.x += e.x;       gin.y += e.y;
  }
  float2 bhn = *(const float2*)&bhh[d0 + 128];
  // wob per softmax col (idx = (tid&31) + 32k)
  float wbv[5];
  #pragma unroll
  for (int k = 0; k < 5; ++k){
    int idx = (tid&31) + 32*k;
    wbv[k] = (idx < VO_) ? wob[idx] : -1e30f;
  }

  // ======== combined-weight register B-fragments: wave w tiles {w,w+8,w+16}
  short8 B0[3], B1[3];
  const int ntile = (w < 5) ? 3 : 2;
  #pragma unroll
  for (int j = 0; j < 3; ++j){
    short8 z = {0,0,0,0,0,0,0,0};
    B0[j] = z; B1[j] = z;
    if (j < ntile){
      int c = (w + 8*j)*16 + l15;
      #pragma unroll
      for (int ks = 0; ks < 2; ++ks){
        int k0 = ks*32 + l4*8;
        float v[8];
        if (c < J3_){
          const float* s = whh + (size_t)c*E_ + k0;
          #pragma unroll
          for (int jj=0;jj<8;jj++) v[jj] = s[jj];
        } else if (c < 192+VO_){
          const float* s = wo + (size_t)(c-192)*E_ + k0;
          #pragma unroll
          for (int jj=0;jj<8;jj++) v[jj] = s[jj];
        } else {
          #pragma unroll
          for (int jj=0;jj<8;jj++) v[jj] = 0.f;
        }
        short8 f;
        #pragma unroll
        for (int jj=0;jj<8;jj++) f[jj] = (short)f2bf(v[jj]);
        if (ks==0) B0[j] = f; else B1[j] = f;
      }
    }
  }

  // ======== h0 = med_table[SOS]; thread holds (row, dims d0..d0+1) ========
  float2 hv2 = *(const float2*)&mt[SOS_*E_ + d0];
  {
    unsigned hv = (unsigned)f2bf(hv2.x) | ((unsigned)f2bf(hv2.y)<<16);
    *(unsigned*)&hA[row*E_ + (d0 ^ ((row&7)<<3))] = hv;
  }
  __syncthreads();

  // ---- prefetch pmed for t=0 ----
  int lm = sLM[row*32];
  float2 pr = *(const float2*)&pmed[(size_t)lm*J3_ + d0];
  float2 pz = *(const float2*)&pmed[(size_t)lm*J3_ + d0 + 64];
  float2 pn = *(const float2*)&pmed[(size_t)lm*J3_ + d0 + 128];

  // ======== main loop: 32 iterations (gh at t, logits for t-1) ========
  for (int t = 0; t <= NSTEP_; ++t){
    short8 A00 = *(const short8*)&hA[l15*E_ + ((l4*8     ) ^ ((l15&7)<<3))];
    short8 A01 = *(const short8*)&hA[l15*E_ + ((32 + l4*8) ^ ((l15&7)<<3))];
    #pragma unroll
    for (int j = 0; j < 3; ++j){
      if (j < ntile){
        f32x4 cc = {0.f,0.f,0.f,0.f};
        cc = __builtin_amdgcn_mfma_f32_16x16x32_bf16(A00, B0[j], cc, 0,0,0);
        cc = __builtin_amdgcn_mfma_f32_16x16x32_bf16(A01, B1[j], cc, 0,0,0);
        int c = (w + 8*j)*16 + l15;
        #pragma unroll
        for (int i=0;i<4;i++) sC[(l4*4+i)*NC_ + c] = cc[i];
      }
    }
    bar_lds();

    // ---- prefetch pmed for t+1 (LOADS issued BEFORE this step's stores) --
    int lmn = 0; float2 npr, npz, npn;
    if (t+1 < NSTEP_){
      lmn = sLM[row*32 + t + 1];
      npr = *(const float2*)&pmed[(size_t)lmn*J3_ + d0];
      npz = *(const float2*)&pmed[(size_t)lmn*J3_ + d0 + 64];
      npn = *(const float2*)&pmed[(size_t)lmn*J3_ + d0 + 128];
    }

    if (t < NSTEP_){
      // ---- pointwise GRU: 2 dims of row `row` ----
      float2 ghr = *(const float2*)&sC[row*NC_ + d0];
      float2 ghz = *(const float2*)&sC[row*NC_ + d0 + 64];
      float2 ghn = *(const float2*)&sC[row*NC_ + d0 + 128];
      {
        float rg = sigmoidf_(gir.x + pr.x + ghr.x);
        float zg = sigmoidf_(giz.x + pz.x + ghz.x);
        float ng = tanhf_(gin.x + pn.x + rg*(ghn.x + bhn.x));
        hv2.x = (1.f - zg)*ng + zg*hv2.x;
      }
      {
        float rg = sigmoidf_(gir.y + pr.y + ghr.y);
        float zg = sigmoidf_(giz.y + pz.y + ghz.y);
        float ng = tanhf_(gin.y + pn.y + rg*(ghn.y + bhn.y));
        hv2.y = (1.f - zg)*ng + zg*hv2.y;
      }
      unsigned hv = (unsigned)f2bf(hv2.x) | ((unsigned)f2bf(hv2.y)<<16);
      *(unsigned*)&hA[row*E_ + (d0 ^ ((row&7)<<3))] = hv;
    }

    if (t >= 1){
      // ---- max-free log_softmax for step t-1 (logits = sC cols 192..324) -
      float lv[5]; float s = 0.f;
      #pragma unroll
      for (int k = 0; k < 5; ++k){
        int idx = (tid&31) + 32*k;
        lv[k] = (idx < VO_) ? (sC[row*NC_ + 192 + idx] + wbv[k]) : -1e30f;
        s += __expf(lv[k]);
      }
      #pragma unroll
      for (int mm=1; mm<32; mm<<=1) s += __shfl_xor(s, mm);  // 32-wide (row)
      float lg = __logf(s);
      size_t ob = ((size_t)grow*NSTEP_ + (t-1))*VO_;
      #pragma unroll
      for (int k = 0; k < 5; ++k){
        int idx = (tid&31) + 32*k;
        if (idx < VO_) out[ob + idx] = lv[k] - lg;
      }
    }
    bar_lds();

    if (t+1 < NSTEP_){ pr = npr; pz = npz; pn = npn; }
  }
}

extern "C" void kernel_launch(void* const* d_in, const int* in_sizes, int n_in,
                              void* d_out, int out_size, void* d_ws, size_t ws_size,
                              hipStream_t stream){
  const int*   dis  = (const int*)  d_in[0];
  const int*   meds = (const int*)  d_in[2];
  const float* dmask= (const float*)d_in[3];
  const float* dt   = (const float*)d_in[6];
  const float* mt   = (const float*)d_in[7];
  const float* aw   = (const float*)d_in[8];
  const float* wih  = (const float*)d_in[10];
  const float* whh  = (const float*)d_in[11];
  const float* bih  = (const float*)d_in[12];
  const float* bhh  = (const float*)d_in[13];
  const float* wo   = (const float*)d_in[14];
  const float* wob  = (const float*)d_in[15];
  float* outp = (float*)d_out;
  float* pmed = (float*)d_ws;                     // 134*192 f32

  k_pmed<<<(134*J3_+255)/256, 256, 0, stream>>>(mt, wih, pmed);
  k_main<<<NROW_/RPB_, 512, 0, stream>>>(dis, dmask, dt, aw, meds,
                                         whh, bhh, wih, bih, wo, wob,
                                         mt, pmed, outp);
}